// Round 11
// baseline (248.211 us; speedup 1.0000x reference)
//
#include <hip/hip_runtime.h>

// ROUND 11 — latency attack: (1) attn register-prefetch double-buffer of
// K/V/mask (overlap HBM latency with compute), (2) LPT block order (big
// causal blocks first), (3) GEMM 64x128 tiles (2-4x more blocks/CU) + same
// register prefetch in the K-loop.
// ws (bf16): qh[3145728] kh[3145728] vh[3145728] wt[4*589824] = 23.6 MB.
// O overwrites qh in place after attention.

#define NEGV (-10000.0f)

typedef __attribute__((ext_vector_type(8))) short v8s;
typedef __attribute__((ext_vector_type(4))) float v4f;
typedef __attribute__((ext_vector_type(8))) unsigned short v8u;

__device__ __forceinline__ unsigned short f2bf(float f) {
  unsigned int u = __float_as_uint(f);
  u += 0x7FFFu + ((u >> 16) & 1u);   // RNE
  return (unsigned short)(u >> 16);
}

// ---------------------------------------------------------------- W transpose
__global__ __launch_bounds__(256) void transpose_w(
    const float* __restrict__ w0, const float* __restrict__ w1,
    const float* __restrict__ w2, const float* __restrict__ w3,
    unsigned short* __restrict__ t0, unsigned short* __restrict__ t1,
    unsigned short* __restrict__ t2, unsigned short* __restrict__ t3) {
  const float* w; unsigned short* t;
  switch (blockIdx.z) {
    case 0: w = w0; t = t0; break;
    case 1: w = w1; t = t1; break;
    case 2: w = w2; t = t2; break;
    default: w = w3; t = t3; break;
  }
  __shared__ unsigned short tile[32][33];
  const int tx = threadIdx.x & 31, ty = threadIdx.x >> 5;
  const int x0 = blockIdx.x * 32, y0 = blockIdx.y * 32;
#pragma unroll
  for (int j = 0; j < 4; j++)
    tile[ty + j * 8][tx] = f2bf(w[(size_t)(y0 + ty + j * 8) * 768 + x0 + tx]);
  __syncthreads();
#pragma unroll
  for (int j = 0; j < 4; j++)
    t[(size_t)(x0 + ty + j * 8) * 768 + y0 + tx] = tile[tx][ty + j * 8];
}

// ---------------------------------------------------------------- GEMM core
// 64x128 tile, 4 waves 2x2 (wave: 32x64), 16x16x32 bf16 MFMA, BK=32,
// register-prefetch double buffering in the K-loop.
template <bool ABF16HEAD, bool CF32ROW>
__device__ __forceinline__ void gemm_core(const void* __restrict__ A,
                                          const unsigned short* __restrict__ Wt,
                                          void* __restrict__ C) {
  const int tid = threadIdx.x;
  const int wave = tid >> 6, lane = tid & 63;
  const int quad = lane >> 4, l16 = lane & 15;
  const int wm = wave >> 1, wn = wave & 1;
  const int bm = blockIdx.x * 64, bn = blockIdx.y * 128;

  __shared__ __align__(16) unsigned short As[64 * 32];
  __shared__ __align__(16) unsigned short Bs[128 * 32];

  v4f acc[2][4];
#pragma unroll
  for (int i = 0; i < 2; i++)
#pragma unroll
    for (int j = 0; j < 4; j++) acc[i][j] = (v4f){0.f, 0.f, 0.f, 0.f};

  // staging indices
  const int ar = tid >> 2, ac0 = (tid & 3) << 3;   // A: 64 rows x 32 k
  const int brr = tid >> 2, bc0 = (tid & 3) << 3;  // B: rows brr, brr+64

  float4 pa0, pa1; uint4 pabf; uint4 pb0, pb1;

  auto prefetch = [&](int kt) {
    int c = kt * 32 + ac0;
    if (ABF16HEAD) {
      int rg = bm + ar;
      size_t aoff = ((size_t)((rg >> 11) * 12 + (c >> 6)) * 2048 +
                     (rg & 2047)) * 64 + (c & 63);
      pabf = *(const uint4*)((const unsigned short*)A + aoff);
    } else {
      const float* Af = (const float*)A;
      size_t aoff = (size_t)(bm + ar) * 768 + c;
      pa0 = *(const float4*)(Af + aoff);
      pa1 = *(const float4*)(Af + aoff + 4);
    }
    pb0 = *(const uint4*)&Wt[(size_t)(bn + brr) * 768 + kt * 32 + bc0];
    pb1 = *(const uint4*)&Wt[(size_t)(bn + 64 + brr) * 768 + kt * 32 + bc0];
  };

  prefetch(0);
  for (int kt = 0; kt < 24; kt++) {
    __syncthreads();
    if (ABF16HEAD) {
      *(uint4*)&As[ar * 32 + ac0] = pabf;
    } else {
      v8u tmp;
      tmp[0] = f2bf(pa0.x); tmp[1] = f2bf(pa0.y);
      tmp[2] = f2bf(pa0.z); tmp[3] = f2bf(pa0.w);
      tmp[4] = f2bf(pa1.x); tmp[5] = f2bf(pa1.y);
      tmp[6] = f2bf(pa1.z); tmp[7] = f2bf(pa1.w);
      *(uint4*)&As[ar * 32 + ac0] = *(uint4*)&tmp;
    }
    *(uint4*)&Bs[brr * 32 + bc0] = pb0;
    *(uint4*)&Bs[(64 + brr) * 32 + bc0] = pb1;
    __syncthreads();
    if (kt < 23) prefetch(kt + 1);

    v8s aF[2], bF[4];
#pragma unroll
    for (int mt = 0; mt < 2; mt++)
      aF[mt] = *(const v8s*)&As[(wm * 32 + mt * 16 + l16) * 32 + quad * 8];
#pragma unroll
    for (int nt = 0; nt < 4; nt++)
      bF[nt] = *(const v8s*)&Bs[(wn * 64 + nt * 16 + l16) * 32 + quad * 8];
#pragma unroll
    for (int mt = 0; mt < 2; mt++)
#pragma unroll
      for (int nt = 0; nt < 4; nt++)
        acc[mt][nt] = __builtin_amdgcn_mfma_f32_16x16x32_bf16(
            aF[mt], bF[nt], acc[mt][nt], 0, 0, 0);
  }

  // epilogue: C/D layout row(m) = quad*4+i, col(n) = l16
#pragma unroll
  for (int mt = 0; mt < 2; mt++) {
#pragma unroll
    for (int i = 0; i < 4; i++) {
      int row = bm + wm * 32 + mt * 16 + quad * 4 + i;
#pragma unroll
      for (int nt = 0; nt < 4; nt++) {
        int col = bn + wn * 64 + nt * 16 + l16;
        if (CF32ROW) {
          ((float*)C)[(size_t)row * 768 + col] = acc[mt][nt][i];
        } else {
          size_t off = ((size_t)((row >> 11) * 12 + (col >> 6)) * 2048 +
                        (row & 2047)) * 64 + (col & 63);
          ((unsigned short*)C)[off] = f2bf(acc[mt][nt][i]);
        }
      }
    }
  }
}

__global__ __launch_bounds__(256) void gemm_qkv(
    const float* __restrict__ xq, const float* __restrict__ xk,
    const float* __restrict__ xv, const unsigned short* __restrict__ wqt,
    const unsigned short* __restrict__ wkt, const unsigned short* __restrict__ wvt,
    unsigned short* __restrict__ qh, unsigned short* __restrict__ kh,
    unsigned short* __restrict__ vh) {
  const float* A; const unsigned short* Wt; unsigned short* C;
  switch (blockIdx.z) {
    case 0: A = xq; Wt = wqt; C = qh; break;
    case 1: A = xk; Wt = wkt; C = kh; break;
    default: A = xv; Wt = wvt; C = vh; break;
  }
  gemm_core<false, false>((const void*)A, Wt, (void*)C);
}

__global__ __launch_bounds__(256) void gemm_o(
    const unsigned short* __restrict__ oat, const unsigned short* __restrict__ wot,
    float* __restrict__ out) {
  gemm_core<true, true>((const void*)oat, wot, (void*)out);
}

// ---------------------------------------------------------------- attention
// grid (32, 24), qt = 31 - bx (LPT: heavy blocks first). 4 waves x 16 q-rows.
// Register-prefetched K/V/mask double buffering; exact causal tile-skip with
// fully-padded-row fallback (phase 1).
__global__ __launch_bounds__(256) void attn_kernel(
    const unsigned short* __restrict__ qh, const unsigned short* __restrict__ kh,
    const unsigned short* __restrict__ vh, const int* __restrict__ attn_mask,
    const int* __restrict__ mask_future, unsigned short* __restrict__ o) {
  const int S = 2048, HD = 64, NH = 12;
  const int qt = 31 - blockIdx.x;           // LPT ordering
  const int bh = blockIdx.y;
  const int b = bh / NH, h = bh % NH;
  const int tid = threadIdx.x;
  const int wave = tid >> 6, lane = tid & 63;
  const int quad = lane >> 4, l16 = lane & 15;

  __shared__ __align__(16) unsigned short Ks[64 * 72];
  __shared__ __align__(16) unsigned short Vt[64 * 72];
  __shared__ __align__(16) unsigned short Ps[4][16 * 72];
  __shared__ int Ms[64];
  __shared__ int s_flag;

  const size_t head_off = (size_t)(b * NH + h) * S * HD;
  const unsigned short* Kb = kh + head_off;
  const unsigned short* Vb = vh + head_off;

  const int mf = mask_future[0];
  if (tid == 0) s_flag = 0;

  const int qrowA = qt * 64 + wave * 16 + l16;
  v8s aQ[2];
  {
    const unsigned short* qp = qh + head_off + (size_t)qrowA * HD + quad * 8;
    aQ[0] = *(const v8s*)(qp);
    aQ[1] = *(const v8s*)(qp + 32);
  }
  const int qbase = qt * 64 + wave * 16 + quad * 4;

  float m_i[4], l_i[4];
  v4f accO[4];
#pragma unroll
  for (int i = 0; i < 4; i++) { m_i[i] = -1e30f; l_i[i] = 0.f; }
#pragma unroll
  for (int dt = 0; dt < 4; dt++) accO[dt] = (v4f){0.f, 0.f, 0.f, 0.f};

  const int kt_causal = mf ? qt : (S / 64 - 1);

  // prefetch regs + staging index decomposition
  const int r0 = tid >> 3, c00 = (tid & 7) << 3;         // idx = tid
  const int r1 = (256 + tid) >> 3, c01 = ((256 + tid) & 7) << 3;
  uint4 pK0, pK1, pV0, pV1;
  int pM;
  auto prefetch = [&](int kt) {
    const uint4* srck = (const uint4*)(Kb + (size_t)kt * 64 * HD);
    const uint4* srcv = (const uint4*)(Vb + (size_t)kt * 64 * HD);
    pK0 = srck[tid];       pK1 = srck[256 + tid];
    pV0 = srcv[tid];       pV1 = srcv[256 + tid];
    if (tid < 64) pM = attn_mask[b * S + kt * 64 + tid];
  };

  for (int phase = 0; phase < 2; phase++) {
    int kt_lo, kt_hi;
    if (phase == 0) { kt_lo = 0; kt_hi = kt_causal; }
    else {
      bool need = (m_i[0] < -5000.f) || (m_i[1] < -5000.f) ||
                  (m_i[2] < -5000.f) || (m_i[3] < -5000.f);
      if (need) s_flag = 1;  // benign 0->1 race
      __syncthreads();
      if (!s_flag) break;
      kt_lo = kt_causal + 1; kt_hi = S / 64 - 1;
      if (kt_lo > kt_hi) break;
    }
    prefetch(kt_lo);
    for (int kt = kt_lo; kt <= kt_hi; kt++) {
      __syncthreads();   // previous iter's LDS reads done
      {
        // K: contiguous 16B writes
        *(uint4*)&Ks[r0 * 72 + c00] = pK0;
        *(uint4*)&Ks[r1 * 72 + c01] = pK1;
        // V: diagonal-swizzled transpose scatter
        v8u vv0 = *(v8u*)&pV0;
        v8u vv1 = *(v8u*)&pV1;
        int sh0 = (tid & 7) << 3, sh1 = ((256 + tid) & 7) << 3;
#pragma unroll
        for (int i = 0; i < 8; i++) {
          int d0 = c00 + i, d1 = c01 + i;
          Vt[d0 * 72 + ((r0 + sh0) & 63)] = vv0[i];
          Vt[d1 * 72 + ((r1 + sh1) & 63)] = vv1[i];
        }
        if (tid < 64) Ms[tid] = pM;
      }
      __syncthreads();
      if (kt < kt_hi) prefetch(kt + 1);

      // S = Q K^T
      v4f sc[4];
#pragma unroll
      for (int nt = 0; nt < 4; nt++) {
        const unsigned short* kp = &Ks[(nt * 16 + l16) * 72 + quad * 8];
        v8s b0 = *(const v8s*)kp;
        v8s b1 = *(const v8s*)(kp + 32);
        v4f z = (v4f){0.f, 0.f, 0.f, 0.f};
        z = __builtin_amdgcn_mfma_f32_16x16x32_bf16(aQ[0], b0, z, 0, 0, 0);
        z = __builtin_amdgcn_mfma_f32_16x16x32_bf16(aQ[1], b1, z, 0, 0, 0);
        sc[nt] = z;
      }

      // scale + causal (additive) + padding (replace) — exact ref semantics
#pragma unroll
      for (int nt = 0; nt < 4; nt++) {
        int key = kt * 64 + nt * 16 + l16;
        bool pad = (Ms[nt * 16 + l16] == 0);
#pragma unroll
        for (int i = 0; i < 4; i++) {
          float v = sc[nt][i] * 0.125f;
          v += (mf && (key > qbase + i)) ? NEGV : 0.f;
          v = pad ? NEGV : v;
          sc[nt][i] = v;
        }
      }

      // online softmax
#pragma unroll
      for (int i = 0; i < 4; i++) {
        float mx = fmaxf(fmaxf(sc[0][i], sc[1][i]), fmaxf(sc[2][i], sc[3][i]));
        mx = fmaxf(mx, __shfl_xor(mx, 1));
        mx = fmaxf(mx, __shfl_xor(mx, 2));
        mx = fmaxf(mx, __shfl_xor(mx, 4));
        mx = fmaxf(mx, __shfl_xor(mx, 8));
        float mnew = fmaxf(m_i[i], mx);
        float alpha = __expf(m_i[i] - mnew);
        m_i[i] = mnew;
        float rs = 0.f;
#pragma unroll
        for (int nt = 0; nt < 4; nt++) {
          float p = __expf(sc[nt][i] - mnew);
          sc[nt][i] = p;
          rs += p;
        }
        rs += __shfl_xor(rs, 1);
        rs += __shfl_xor(rs, 2);
        rs += __shfl_xor(rs, 4);
        rs += __shfl_xor(rs, 8);
        l_i[i] = l_i[i] * alpha + rs;
#pragma unroll
        for (int dt = 0; dt < 4; dt++) accO[dt][i] *= alpha;
      }

      // P: C-layout regs -> per-wave LDS -> A-layout frags
#pragma unroll
      for (int nt = 0; nt < 4; nt++)
#pragma unroll
        for (int i = 0; i < 4; i++)
          Ps[wave][(quad * 4 + i) * 72 + nt * 16 + l16] = f2bf(sc[nt][i]);

#pragma unroll
      for (int ks = 0; ks < 2; ks++) {
        v8s aP = *(const v8s*)&Ps[wave][l16 * 72 + ks * 32 + quad * 8];
#pragma unroll
        for (int dt = 0; dt < 4; dt++) {
          int d = dt * 16 + l16;
          int scol = ((ks * 32 + quad * 8) + ((d >> 3) << 3)) & 63;
          v8s bV = *(const v8s*)&Vt[d * 72 + scol];
          accO[dt] =
              __builtin_amdgcn_mfma_f32_16x16x32_bf16(aP, bV, accO[dt], 0, 0, 0);
        }
      }
    }
    if (phase == 0) __syncthreads();  // all waves done before flag vote
  }

  // normalize + store O bf16 head-major over own Q region (in place)
#pragma unroll
  for (int i = 0; i < 4; i++) {
    float inv = 1.f / l_i[i];
    int qr = qbase + i;
    size_t base = head_off + (size_t)qr * HD;
#pragma unroll
    for (int dt = 0; dt < 4; dt++)
      o[base + dt * 16 + l16] = f2bf(accO[dt][i] * inv);
  }
}

// ---------------------------------------------------------------- launch
extern "C" void kernel_launch(void* const* d_in, const int* in_sizes, int n_in,
                              void* d_out, int out_size, void* d_ws, size_t ws_size,
                              hipStream_t stream) {
  const float* q  = (const float*)d_in[0];
  const float* k  = (const float*)d_in[1];
  const float* v  = (const float*)d_in[2];
  const int* amask = (const int*)d_in[3];
  const float* Wq = (const float*)d_in[4];
  const float* Wk = (const float*)d_in[5];
  const float* Wv = (const float*)d_in[6];
  const float* Wo = (const float*)d_in[7];
  const int* mf  = (const int*)d_in[8];
  float* out = (float*)d_out;

  unsigned short* ws = (unsigned short*)d_ws;
  unsigned short* qh = ws;                  // O overwrites qh after attention
  unsigned short* kh = qh + 3145728;
  unsigned short* vh = kh + 3145728;
  unsigned short* wqt = vh + 3145728;
  unsigned short* wkt = wqt + 589824;
  unsigned short* wvt = wkt + 589824;
  unsigned short* wot = wvt + 589824;

  transpose_w<<<dim3(24, 24, 4), 256, 0, stream>>>(Wq, Wk, Wv, Wo,
                                                   wqt, wkt, wvt, wot);
  gemm_qkv<<<dim3(64, 6, 3), 256, 0, stream>>>(q, k, v, wqt, wkt, wvt,
                                               qh, kh, vh);
  attn_kernel<<<dim3(32, 24), 256, 0, stream>>>(qh, kh, vh, amask, mf, qh);
  gemm_o<<<dim3(64, 6), 256, 0, stream>>>(qh, wot, out);
}